// Round 17
// baseline (141.657 us; speedup 1.0000x reference)
//
#include <hip/hip_runtime.h>
#include <hip/hip_bf16.h>

typedef __attribute__((ext_vector_type(8))) short bf16x8;
typedef __attribute__((ext_vector_type(4))) float f32x4;
typedef unsigned long long ull;

#define MFMA(a,b,c) __builtin_amdgcn_mfma_f32_16x16x32_bf16((a),(b),(c),0,0,0)
#define VMCNT(N) asm volatile("s_waitcnt vmcnt(%0)" :: "i"(N) : "memory")
#define EXP2(x) __builtin_amdgcn_exp2f(x)

__device__ __forceinline__ short f2bs(float f){
  union { float f; unsigned u; } x; x.f = f;
  unsigned r = (x.u + 0x7fffu + ((x.u >> 16) & 1u)) >> 16;
  return (short)r;
}
__device__ __forceinline__ float bs2f(short s){
  union { unsigned u; float f; } x; x.u = ((unsigned)(unsigned short)s) << 16;
  return x.f;
}

// async global->LDS, 16B per lane. LDS dest = wave-uniform base + lane*16.
__device__ __forceinline__ void gl2lds16(const void* g, void* l){
  __builtin_amdgcn_global_load_lds((const __attribute__((address_space(1))) void*)g,
                                   (__attribute__((address_space(3))) void*)l, 16, 0, 0);
}

__device__ __forceinline__ void merge2(ull& a1, ull& a2, ull b1, ull b2){
  ull n1 = min(a1, b1);
  ull n2 = min(max(a1, b1), min(a2, b2));
  a1 = n1; a2 = n2;
}

// ---------------- kernel 0: weight convert + G transpose ----------------
__global__ __launch_bounds__(256) void prep_kernel(const float* __restrict__ xffw,
                                                   const float* __restrict__ w1,
                                                   const float* __restrict__ w2,
                                                   const float* __restrict__ G,
                                                   short* __restrict__ wqkv_b,
                                                   short* __restrict__ w1_b,
                                                   short* __restrict__ w2_b,
                                                   short* __restrict__ gt){
  __shared__ float tile[32][33];
  int blk = blockIdx.x;
  if (blk >= 1024){
    int i = (blk-1024)*256 + threadIdx.x;
    int stride = 32*256;
    for (int idx = i; idx < 384*128; idx += stride) wqkv_b[idx] = f2bs(xffw[idx]);
    for (int idx = i; idx < 128*128; idx += stride) w1_b[idx] = f2bs(w1[idx]);
    for (int idx = i; idx < 128*128; idx += stride) w2_b[idx] = f2bs(w2[idx]);
    return;
  }
  int bx = blk & 31;
  int by = blk >> 5;
  int tx = threadIdx.x & 31, ty = threadIdx.x >> 5;
  #pragma unroll
  for (int j=0;j<4;j++){
    int n = by*32 + ty + j*8;
    tile[ty+j*8][tx] = G[(size_t)n*1024 + bx*32 + tx];
  }
  __syncthreads();
  #pragma unroll
  for (int j=0;j<4;j++){
    int m = bx*32 + ty + j*8;
    gt[(size_t)m*1024 + by*32 + tx] = f2bs(tile[tx][ty+j*8]);
  }
}

// ---------------- kernel 1: QKV projection ----------------
__global__ __launch_bounds__(256,3) void qkv_kernel(const float* __restrict__ inp,
                                                  const short* __restrict__ wqkv,
                                                  const float* __restrict__ bias,
                                                  short* __restrict__ q, short* __restrict__ kT,
                                                  short* __restrict__ nvt){
  __shared__ __align__(16) char smem[49152];
  int w = threadIdx.x >> 6, lane = threadIdx.x & 63;
  int lr = lane & 15, lg = lane >> 4;
  int r0 = blockIdx.x*64;
  int bt = blockIdx.x >> 4;
  int n0 = r0 & 1023;
  int rw = r0 + w*16;
  bf16x8 a[4];
  #pragma unroll
  for (int kc=0;kc<4;kc++){
    const float* ar = inp + (size_t)(rw+lr)*128 + kc*32 + lg*8;
    float4 f0 = *(const float4*)ar;
    float4 f1 = *(const float4*)(ar+4);
    bf16x8 t;
    t[0]=f2bs(f0.x); t[1]=f2bs(f0.y); t[2]=f2bs(f0.z); t[3]=f2bs(f0.w);
    t[4]=f2bs(f1.x); t[5]=f2bs(f1.y); t[6]=f2bs(f1.z); t[7]=f2bs(f1.w);
    a[kc]=t;
  }
  auto stageW = [&](int buf, int kc){
    #pragma unroll
    for (int t=0;t<6;t++){
      int r = (w*6+t)*16 + (lane>>2);
      int s = (lane&3) ^ ((r>>1)&3);
      gl2lds16(wqkv + (size_t)r*128 + kc*32 + s*8,
               smem + buf*24576 + (w*6+t)*1024);
    }
  };
  f32x4 acc[24];
  #pragma unroll
  for (int j=0;j<24;j++) acc[j] = f32x4{0.f,0.f,0.f,0.f};
  stageW(0, 0);
  int cur = 0;
  for (int kc=0; kc<4; kc++){
    if (kc < 3) { stageW(cur^1, kc+1); VMCNT(6); } else { VMCNT(0); }
    __builtin_amdgcn_s_barrier();
    __builtin_amdgcn_sched_barrier(0);
    const char* wb = smem + cur*24576;
    __builtin_amdgcn_s_setprio(1);
    #pragma unroll
    for (int jt=0;jt<24;jt++){
      int j = jt*16 + lr;
      bf16x8 b = *(const bf16x8*)(wb + (size_t)j*64 + ((lg ^ ((lr>>1)&3))*16));
      acc[jt] = MFMA(a[kc], b, acc[jt]);
    }
    __builtin_amdgcn_s_setprio(0);
    __builtin_amdgcn_s_barrier();
    cur ^= 1;
  }
  #pragma unroll
  for (int jt=0;jt<8;jt++){
    float bj = bias[jt*16+lr];
    #pragma unroll
    for (int rr=0;rr<4;rr++)
      q[(size_t)(rw + lg*4 + rr)*128 + jt*16 + lr] = f2bs(acc[jt][rr] + bj);
  }
  __syncthreads();
  short (*tb)[72] = (short(*)[72])smem;
  #pragma unroll
  for (int jt=8;jt<16;jt++){
    int d = (jt-8)*16 + lr;
    float bj = bias[jt*16+lr];
    #pragma unroll
    for (int rr=0;rr<4;rr++) tb[d][w*16 + lg*4 + rr] = f2bs(acc[jt][rr] + bj);
  }
  __syncthreads();
  #pragma unroll
  for (int it=0;it<4;it++){
    int idx = it*256 + threadIdx.x;
    int row = idx >> 3, c8 = (idx & 7)*8;
    *(bf16x8*)(kT + ((size_t)bt*128 + row)*1024 + n0 + c8) = *(const bf16x8*)&tb[row][c8];
  }
  __syncthreads();
  #pragma unroll
  for (int jt=16;jt<24;jt++){
    int c = (jt-16)*16 + lr;
    float bj = bias[jt*16+lr];
    #pragma unroll
    for (int rr=0;rr<4;rr++) tb[c][w*16 + lg*4 + rr] = f2bs(acc[jt][rr] + bj);
  }
  __syncthreads();
  #pragma unroll
  for (int it=0;it<4;it++){
    int idx = it*256 + threadIdx.x;
    int row = idx >> 3, c8 = (idx & 7)*8;
    *(bf16x8*)(nvt + ((size_t)bt*128 + row)*1024 + n0 + c8) = *(const bf16x8*)&tb[row][c8];
  }
}

// ---------------- kernel 2: KGT = (K^T G)*log2e/sqrt(128) ----------------
__global__ __launch_bounds__(256,3) void kg_kernel(const short* __restrict__ gt,
                                                   const short* __restrict__ kT,
                                                   short* __restrict__ kgt){
  __shared__ __align__(16) short gtl[2][64*64];
  __shared__ __align__(16) short ktl[2][128*64];
  int lb = (blockIdx.x & 7)*96 + (blockIdx.x >> 3);   // XCD swizzle
  int bt = lb >> 4;
  int mt = lb & 15;
  int w = threadIdx.x>>6, lane = threadIdx.x&63, lr = lane&15, lg = lane>>4;
  int mblk = mt*64;
  const short* kbase = kT + (size_t)bt*128*1024;
  auto stage = [&](int b, int nc){
    int n0 = nc*64;
    #pragma unroll
    for (int t=0;t<2;t++){
      int row = w*16 + t*8 + (lane>>3);
      int cswz = ((lane&7)*16) ^ ((row&7)<<4);
      gl2lds16(gt + (size_t)(mblk+row)*1024 + n0 + (cswz>>1),
               (char*)gtl[b] + w*2048 + t*1024);
    }
    #pragma unroll
    for (int t=0;t<4;t++){
      int row = w*32 + t*8 + (lane>>3);
      int cswz = ((lane&7)*16) ^ ((row&7)<<4);
      gl2lds16(kbase + (size_t)row*1024 + n0 + (cswz>>1),
               (char*)ktl[b] + w*4096 + t*1024);
    }
  };
  f32x4 acc[8];
  #pragma unroll
  for (int i=0;i<8;i++) acc[i] = f32x4{0.f,0.f,0.f,0.f};
  stage(0, 0);
  int cur = 0;
  for (int nc=0; nc<16; nc++){
    if (nc < 15) { stage(cur^1, nc+1); VMCNT(6); } else { VMCNT(0); }
    __builtin_amdgcn_s_barrier();
    __builtin_amdgcn_sched_barrier(0);
    __builtin_amdgcn_s_setprio(1);
    #pragma unroll
    for (int ks=0;ks<2;ks++){
      int arl = w*16 + lr;
      int acb = ks*64 + lg*16;
      bf16x8 af = *(const bf16x8*)((const char*)gtl[cur] + arl*128 + (acb ^ ((arl&7)<<4)));
      #pragma unroll
      for (int dt=0;dt<8;dt++){
        int brl = dt*16 + lr;
        bf16x8 bf = *(const bf16x8*)((const char*)ktl[cur] + brl*128 + (acb ^ ((brl&7)<<4)));
        acc[dt] = MFMA(af, bf, acc[dt]);
      }
    }
    __builtin_amdgcn_s_setprio(0);
    __builtin_amdgcn_s_barrier();
    cur ^= 1;
  }
  // 1/sqrt(128) * log2(e): exps downstream become single v_exp (exp2)
  const float SCALE = 0.08838834764831845f * 1.4426950408889634f;
  int m = mblk + w*16 + lg*4;
  #pragma unroll
  for (int dt=0;dt<8;dt++){
    #pragma unroll
    for (int rr=0;rr<4;rr++){
      kgt[((size_t)(bt*1024 + m + rr))*128 + dt*16 + lr] = f2bs(acc[dt][rr]*SCALE);
    }
  }
}

// ---------------- kernel 3: FUSED attn, phase-alternating; R12 XOR p-layout ----------------
// LDS = 16KB kgl + 16KB nvl + 8KB p = 40960B.
__global__ __launch_bounds__(256,3) void fused_kernel(const short* __restrict__ q,
                                                      const short* __restrict__ kgt,
                                                      const short* __restrict__ nvt,
                                                      float* __restrict__ zbuf,
                                                      short* __restrict__ pbuf,
                                                      short* __restrict__ vib){
  __shared__ __align__(16) short kgl[64*128];
  __shared__ __align__(16) short nvl[128*64];
  __shared__ __align__(16) char  p_raw[8192];   // [wave][16][64] bf16, byte ^= (row&7)<<4
  int lb = (blockIdx.x & 7)*96 + (blockIdx.x >> 3);   // XCD swizzle
  int bt = lb >> 4;
  int rblk = lb & 15;
  int w = threadIdx.x>>6, lane = threadIdx.x&63, lr = lane&15, lg = lane>>4;
  int r0 = rblk*64 + w*16;
  bool is5 = (bt % 12) == 5;
  int bq = bt / 12;
  const short* qrow = q + ((size_t)(bt*1024 + r0 + lr))*128;
  bf16x8 a[4];
  #pragma unroll
  for (int kc=0;kc<4;kc++) a[kc] = *(const bf16x8*)(qrow + kc*32 + lg*8);
  const short* kgb = kgt + (size_t)bt*1024*128;
  const short* nvb = nvt + (size_t)bt*128*1024;
  char* pw = p_raw + w*2048;
  auto stage_kg = [&](int mc){
    int m0 = mc*64;
    #pragma unroll
    for (int t=0;t<4;t++){
      int row = w*16 + t*4 + (lane>>4);
      int cswz = ((lane&15)*16) ^ ((row&7)<<4);
      gl2lds16(kgb + (size_t)(m0+row)*128 + (cswz>>1),
               (char*)kgl + w*4096 + t*1024);
    }
  };
  auto stage_nv = [&](int mc){
    int m0 = mc*64;
    #pragma unroll
    for (int t=0;t<4;t++){
      int row = w*32 + t*8 + (lane>>3);
      int cswz = ((lane&7)*16) ^ ((row&7)<<4);
      gl2lds16(nvb + (size_t)row*1024 + m0 + (cswz>>1),
               (char*)nvl + w*4096 + t*1024);
    }
  };
  f32x4 acc[8];
  #pragma unroll
  for (int i=0;i<8;i++) acc[i] = f32x4{0.f,0.f,0.f,0.f};
  float zacc[4] = {0.f,0.f,0.f,0.f};
  // prologue
  stage_kg(0);
  stage_nv(0);
  VMCNT(0);
  __builtin_amdgcn_s_barrier();
  __builtin_amdgcn_sched_barrier(0);
  for (int mc=0; mc<16; mc++){
    int m0 = mc*64;
    // ---- e-phase: reads kgl only ----
    __builtin_amdgcn_s_setprio(1);
    #pragma unroll
    for (int s=0;s<4;s++){
      f32x4 e = f32x4{0.f,0.f,0.f,0.f};
      #pragma unroll
      for (int kc=0;kc<4;kc++){
        int rl = s*16 + lr;
        int cb = kc*64 + lg*16;
        bf16x8 kb = *(const bf16x8*)((const char*)kgl + rl*256 + (cb ^ ((rl&7)<<4)));
        e = MFMA(a[kc], kb, e);
      }
      #pragma unroll
      for (int rr=0;rr<4;rr++){
        int row = lg*4+rr;
        float p = EXP2(fminf(e[rr], 80.f));   // kgt carries log2e; raw v_exp_f32
        zacc[rr] += p;
        *(short*)(pw + ((row*128 + (s*16+lr)*2) ^ ((row&7)<<4))) = f2bs(p);
      }
    }
    __builtin_amdgcn_s_setprio(0);
    __builtin_amdgcn_s_barrier();           // kgl reads done everywhere
    if (mc < 15) stage_kg(mc+1);            // overwrite kgl; overlaps PV
    if (mc < 15) { VMCNT(4); } else { VMCNT(0); }  // nv(mc) landed
    __builtin_amdgcn_s_barrier();
    __builtin_amdgcn_sched_barrier(0);
    // ---- PV phase: reads p (own wave, single b128) + nvl ----
    bf16x8 pa0 = *(const bf16x8*)(pw + ((lr*128 + lg*16) ^ ((lr&7)<<4)));
    bf16x8 pa1 = *(const bf16x8*)(pw + ((lr*128 + 64 + lg*16) ^ ((lr&7)<<4)));
    __builtin_amdgcn_s_setprio(1);
    #pragma unroll
    for (int ct=0; ct<8; ct++){
      int c = ct*16 + lr;
      int mb0 = lg*16;
      int mb1 = 64 + lg*16;
      bf16x8 nb0 = *(const bf16x8*)((const char*)nvl + c*128 + (mb0 ^ ((c&7)<<4)));
      bf16x8 nb1 = *(const bf16x8*)((const char*)nvl + c*128 + (mb1 ^ ((c&7)<<4)));
      acc[ct] = MFMA(pa0, nb0, acc[ct]);
      acc[ct] = MFMA(pa1, nb1, acc[ct]);
    }
    __builtin_amdgcn_s_setprio(0);
    if (is5){
      // dump unnormalized P tile (bf16) for deterministic col-sums
      #pragma unroll
      for (int tt=0; tt<4; tt++){
        int row = tt*4 + (lane>>4);     // 0..15
        int m = (lane&15)*4;            // 0..60
        ull v = *(const ull*)(pw + ((row*128 + m*2) ^ ((row&7)<<4)));
        *(ull*)(pbuf + ((size_t)bq*1024 + r0 + row)*1024 + m0 + m) = v;
      }
    }
    __builtin_amdgcn_s_barrier();           // nvl reads done everywhere
    if (mc < 15) { stage_nv(mc+1); VMCNT(4); } else { VMCNT(0); }  // kg(mc+1) landed
    __builtin_amdgcn_s_barrier();
    __builtin_amdgcn_sched_barrier(0);
  }
  // z: reduce across the 16 lr lanes (cols)
  #pragma unroll
  for (int d=1;d<16;d<<=1){
    #pragma unroll
    for (int rr=0;rr<4;rr++) zacc[rr] += __shfl_xor(zacc[rr], d, 64);
  }
  if (lr==0){
    #pragma unroll
    for (int rr=0;rr<4;rr++) zbuf[(size_t)bt*1024 + r0 + lg*4 + rr] = zacc[rr];
  }
  float inv[4];
  #pragma unroll
  for (int rr=0;rr<4;rr++) inv[rr] = 1.0f/zacc[rr];
  #pragma unroll
  for (int ct=0;ct<8;ct++){
    #pragma unroll
    for (int rr=0;rr<4;rr++){
      vib[((size_t)(bt*1024 + r0 + lg*4 + rr))*128 + ct*16 + lr] = f2bs(acc[ct][rr]*inv[rr]);
    }
  }
}

// ---------------- kernel 3b: deterministic col sums from dumped P ----------------
__global__ __launch_bounds__(256) void colsum_kernel(const short* __restrict__ pbuf,
                                                     const float* __restrict__ zbuf,
                                                     float* __restrict__ csfinal){
  __shared__ float part[4][64];
  int b = blockIdx.x >> 4, mg = blockIdx.x & 15;
  int t = threadIdx.x;
  int mcol = mg*64 + (t & 63);
  int rq = t >> 6;
  const short* pb = pbuf + (size_t)b*1024*1024;
  const float* zb = zbuf + (size_t)(b*12 + 5)*1024;
  float s = 0.f;
  for (int r = rq*256; r < rq*256 + 256; r++){
    s += bs2f(pb[(size_t)r*1024 + mcol]) * (1.0f/zb[r]);
  }
  part[rq][t & 63] = s;
  __syncthreads();
  if (t < 64){
    float cs = (part[0][t] + part[1][t]) + (part[2][t] + part[3][t]);
    csfinal[(size_t)b*1024 + mg*64 + t] = cs;
  }
}

// ---------------- kernel 4: parallel deterministic top-2-min -> y per batch ----------------
__global__ __launch_bounds__(256) void top2_kernel(const float* __restrict__ csfinal,
                                                   int* __restrict__ yidx){
  __shared__ ull s1[4], s2[4];
  int b = blockIdx.x;
  ull b1 = ~0ull, b2 = ~0ull;
  #pragma unroll
  for (int j=0;j<4;j++){
    int col = j*256 + threadIdx.x;
    float s = csfinal[(size_t)b*1024 + col];
    union { float f; unsigned u; } cv; cv.f = s;
    ull key = ((ull)cv.u << 32) | (unsigned)col;
    merge2(b1, b2, key, ~0ull);
  }
  #pragma unroll
  for (int d=1;d<64;d<<=1){
    ull o1 = __shfl_xor(b1, d, 64);
    ull o2 = __shfl_xor(b2, d, 64);
    merge2(b1, b2, o1, o2);
  }
  int w = threadIdx.x >> 6;
  if ((threadIdx.x & 63) == 0){ s1[w] = b1; s2[w] = b2; }
  __syncthreads();
  if (threadIdx.x == 0){
    ull r1 = s1[0], r2 = s2[0];
    merge2(r1, r2, s1[1], s2[1]);
    merge2(r1, r2, s1[2], s2[2]);
    merge2(r1, r2, s1[3], s2[3]);
    yidx[b] = (int)(r2 & 0xffffffffu);
  }
}

// ---------------- kernel 5: mixup averages from pristine NV ----------------
__global__ void nvfixA_kernel(const short* __restrict__ nvt, const int* __restrict__ yidx,
                              float* __restrict__ mixres){
  int bt = blockIdx.x; int b = bt/12, t = bt%12;
  int y = yidx[b];
  int y_start = max(y-6, 0), y_end = min(y+12, 1024);
  int bs, j0, cnt;
  if (y_end > 1024-6){ bs = 1; j0 = y_start; cnt = y_end - y_start; }
  else { bs = 6; j0 = y_start/6; cnt = y_end/6 - j0; }
  int items = bs*78;
  int idx = threadIdx.x;
  if (idx >= items) return;
  int i = idx / 78, c = idx % 78;
  const short* nvb = nvt + (size_t)bt*128*1024;
  float acc = 0.f;
  for (int jj=0;jj<cnt;jj++){
    int col = (j0+jj)*bs + i;
    float gv;
    if (t == 5 && col == y){
      float wsum = 0.f, mv = 0.f;
      #pragma unroll
      for (int tp=0;tp<5;tp++){
        float d = (float)tp - 4.0f;
        float w = __expf(-d*d/200.0f);
        wsum += w;
        mv += w * bs2f(nvt[((size_t)(b*12+tp)*128 + c)*1024 + y]);
      }
      gv = mv / wsum;
    } else {
      gv = bs2f(nvb[(size_t)c*1024 + col]);
    }
    acc += gv;
  }
  mixres[((size_t)bt*6 + i)*78 + c] = acc / (float)cnt;
}

// ---------------- kernel 7: FFN + rank<=6 correction + residual + LN; half-K staging ----------------
// LDS: wl 16384 (one k-half) + hb 16896 = 33280 -> 4 blocks/CU.
__global__ __launch_bounds__(256,4) void ffn_kernel(const short* __restrict__ vib,
                                                  const float* __restrict__ inp,
                                                  const short* __restrict__ w1b,
                                                  const short* __restrict__ w2b,
                                                  const float* __restrict__ b1,
                                                  const float* __restrict__ b2,
                                                  const float* __restrict__ lnw,
                                                  const float* __restrict__ lnb,
                                                  const short* __restrict__ qb,
                                                  const short* __restrict__ kgt,
                                                  const short* __restrict__ nvt,
                                                  const float* __restrict__ mixres,
                                                  const float* __restrict__ zbuf,
                                                  const int* __restrict__ yidx,
                                                  float* __restrict__ out){
  __shared__ __align__(16) short wl[128*64];        // 16384: [row][64-col half], XOR slots
  __shared__ __align__(16) char  hb[16896];         // union: prologue then h (pitch 132)
  short* kcolT = (short*)hb;                        // [16][136] shorts, 4352 B
  float* delta = (float*)(hb + 4352);               // [6][80] f32, 1920 B
  float* p_sh  = (float*)(hb + 4352 + 1920);        // [64][6] f32, 1536 B
  short* hs    = (short*)hb;                        // [(w*16+row)*132 + col] after GEMM1
  int w = threadIdx.x>>6, lane = threadIdx.x&63, lr = lane&15, lg = lane>>4;
  int bt = blockIdx.x >> 4;
  int nb = (blockIdx.x & 15)*64;      // local row base within bt
  int r0 = blockIdx.x*64 + w*16;      // global row base of this wave
  int b = bt/12;
  int y = yidx[b];
  int y_end = min(y+12, 1024);
  int bs = (y_end > 1024-6) ? 1 : 6;
  // stage one k-half of a [128][128] weight: rows 0..127, cols half*64..+64
  auto stageH = [&](const short* src, int half){
    #pragma unroll
    for (int t=0;t<4;t++){
      int r = (w*4+t)*8 + (lane>>3);
      int s = (lane&7) ^ (r&7);
      gl2lds16(src + (size_t)r*128 + half*64 + s*8, (char*)wl + (w*4+t)*1024);
    }
  };
  stageH(w1b, 0);                                   // in flight during whole prologue
  // vib A-frag prefetch (independent of prologue)
  bf16x8 av[4];
  #pragma unroll
  for (int kc=0;kc<4;kc++) av[kc] = *(const bf16x8*)(vib + (size_t)(r0+lr)*128 + kc*32 + lg*8);
  // phase A: kcolT + delta
  for (int idx = threadIdx.x; idx < 16*128; idx += 256){
    int i = idx >> 7, d = idx & 127;
    kcolT[i*136 + d] = (i < bs) ? kgt[((size_t)(bt*1024 + y + i))*128 + d] : (short)0;
  }
  for (int idx = threadIdx.x; idx < 6*78; idx += 256){
    int i = idx / 78, c = idx % 78;
    float dv = 0.f;
    if (i < bs){
      float avg = mixres[((size_t)bt*6 + i)*78 + c];
      int ti = (int)avg;                   // trunc toward zero
      unsigned char u = (unsigned char)ti; // wrap mod 256
      dv = (float)u - bs2f(nvt[((size_t)bt*128 + c)*1024 + (y+i)]);
    }
    delta[i*80 + c] = dv;
  }
  __syncthreads();   // sync1: kcolT ready (w1h0 + vib also drained)
  // phase B: p via MFMA (same operand layout as fused => bit-identical e)
  {
    const short* qr = qb + ((size_t)(bt*1024 + nb + w*16 + lr))*128;
    bf16x8 qa[4];
    #pragma unroll
    for (int kc=0;kc<4;kc++) qa[kc] = *(const bf16x8*)(qr + kc*32 + lg*8);
    f32x4 ep = f32x4{0.f,0.f,0.f,0.f};
    #pragma unroll
    for (int kc=0;kc<4;kc++){
      bf16x8 kb = *(const bf16x8*)((const char*)kcolT + lr*272 + kc*64 + lg*16);
      ep = MFMA(qa[kc], kb, ep);
    }
    #pragma unroll
    for (int rr=0;rr<4;rr++){
      int row = w*16 + lg*4 + rr;          // block-local 0..63
      float pv = 0.f;
      if (lr < bs){
        float z = zbuf[(size_t)bt*1024 + nb + row];
        pv = EXP2(fminf(ep[rr], 80.f)) / z;
      }
      if (lr < 6) p_sh[row*6 + lr] = pv;
    }
  }
  __syncthreads();   // sync2: p_sh/delta ready everywhere
  // corrected A-frags
  float pr6[6];
  #pragma unroll
  for (int i=0;i<6;i++) pr6[i] = p_sh[(w*16 + lr)*6 + i];
  bf16x8 a[4];
  #pragma unroll
  for (int kc=0;kc<4;kc++){
    bf16x8 v = av[kc];
    #pragma unroll
    for (int e=0;e<8;e++){
      int col = kc*32 + lg*8 + e;
      if (col < 78){
        float ds = 0.f;
        #pragma unroll
        for (int i=0;i<6;i++) ds += pr6[i] * delta[i*80 + col];
        v[e] = f2bs(bs2f(v[e]) + ds);
      }
    }
    a[kc] = v;
  }
  // GEMM1 half 0 (kc=0,1); wl holds w1 cols 0..63 (landed at sync1)
  f32x4 acc[8];
  #pragma unroll
  for (int i=0;i<8;i++) acc[i] = f32x4{0.f,0.f,0.f,0.f};
  __builtin_amdgcn_s_setprio(1);
  #pragma unroll
  for (int kc=0;kc<2;kc++){
    #pragma unroll
    for (int jt=0;jt<8;jt++){
      int jr = jt*16 + lr;
      bf16x8 bfr = *(const bf16x8*)((const char*)wl + (size_t)jr*128 + (((kc*4+lg) ^ (jr&7))*16));
      acc[jt] = MFMA(a[kc], bfr, acc[jt]);
    }
  }
  __builtin_amdgcn_s_setprio(0);
  __syncthreads();   // sync3: half0 reads done; prologue hb reads done
  stageH(w1b, 1);
  __syncthreads();   // sync4: half1 landed
  __builtin_amdgcn_s_setprio(1);
  #pragma unroll
  for (int kc=2;kc<4;kc++){
    #pragma unroll
    for (int jt=0;jt<8;jt++){
      int jr = jt*16 + lr;
      bf16x8 bfr = *(const bf16x8*)((const char*)wl + (size_t)jr*128 + ((((kc-2)*4+lg) ^ (jr&7))*16));
      acc[jt] = MFMA(a[kc], bfr, acc[jt]);
    }
  }
  __builtin_amdgcn_s_setprio(0);
  // gelu -> h (wave-local rows of hs; hb prologue data dead since sync3)
  #pragma unroll
  for (int jt=0;jt<8;jt++){
    float bj = b1[jt*16+lr];
    #pragma unroll
    for (int rr=0;rr<4;rr++){
      float x = acc[jt][rr] + bj;
      float g = 0.5f*x*(1.0f + erff(x*0.70710678118654752f));
      hs[(w*16 + lg*4 + rr)*132 + jt*16 + lr] = f2bs(g);
    }
  }
  __syncthreads();   // sync5: w1h1 reads done (free wl for w2)
  stageH(w2b, 0);
  // ha: wave-local hs reads (same-wave write->read, lgkmcnt ordering suffices)
  bf16x8 ha[4];
  #pragma unroll
  for (int kc=0;kc<4;kc++){
    const short* hp = &hs[(w*16 + lr)*132 + kc*32 + lg*8];
    ull lo = *(const ull*)hp;
    ull hi = *(const ull*)(hp + 4);
    ((ull*)&ha[kc])[0] = lo; ((ull*)&ha[kc])[1] = hi;
  }
  __syncthreads();   // sync6: w2h0 landed
  f32x4 acc2[8];
  #pragma unroll
  for (int i=0;i<8;i++) acc2[i] = f32x4{0.f,0.f,0.f,0.f};
  __builtin_amdgcn_s_setprio(1);
  #pragma unroll
  for (int kc=0;kc<2;kc++){
    #pragma unroll
    for (int jt=0;jt<8;jt++){
      int jr = jt*16 + lr;
      bf16x8 bfr = *(const bf16x8*)((const char*)wl + (size_t)jr*128 + (((kc*4+lg) ^ (jr&7))*16));
      acc2[jt] = MFMA(ha[kc], bfr, acc2[jt]);
    }
  }
  __builtin_amdgcn_s_setprio(0);
  __syncthreads();   // sync7: half0 reads done
  stageH(w2b, 1);
  // prefetch inp (residual) while w2h1 lands
  float rin[8][4];
  #pragma unroll
  for (int jt=0;jt<8;jt++)
    #pragma unroll
    for (int rr=0;rr<4;rr++)
      rin[jt][rr] = inp[(size_t)(r0 + lg*4 + rr)*128 + jt*16 + lr];
  __syncthreads();   // sync8: w2h1 landed
  __builtin_amdgcn_s_setprio(1);
  #pragma unroll
  for (int kc=2;kc<4;kc++){
    #pragma unroll
    for (int jt=0;jt<8;jt++){
      int jr = jt*16 + lr;
      bf16x8 bfr = *(const bf16x8*)((const char*)wl + (size_t)jr*128 + ((((kc-2)*4+lg) ^ (jr&7))*16));
      acc2[jt] = MFMA(ha[kc], bfr, acc2[jt]);
    }
  }
  __builtin_amdgcn_s_setprio(0);
  float xv[8][4];
  #pragma unroll
  for (int jt=0;jt<8;jt++){
    float bj = b2[jt*16+lr];
    #pragma unroll
    for (int rr=0;rr<4;rr++){
      xv[jt][rr] = acc2[jt][rr] + bj + rin[jt][rr];
    }
  }
  float mu[4], rstd[4];
  #pragma unroll
  for (int rr=0;rr<4;rr++){
    float s = 0.f;
    #pragma unroll
    for (int jt=0;jt<8;jt++) s += xv[jt][rr];
    #pragma unroll
    for (int m=1;m<16;m<<=1) s += __shfl_xor(s, m, 64);
    mu[rr] = s * (1.0f/128.0f);
  }
  #pragma unroll
  for (int rr=0;rr<4;rr++){
    float s = 0.f;
    #pragma unroll
    for (int jt=0;jt<8;jt++){ float d = xv[jt][rr]-mu[rr]; s += d*d; }
    #pragma unroll
    for (int m=1;m<16;m<<=1) s += __shfl_xor(s, m, 64);
    rstd[rr] = rsqrtf(s * (1.0f/128.0f) + 1e-5f);
  }
  #pragma unroll
  for (int jt=0;jt<8;jt++){
    int col = jt*16 + lr;
    float lw = lnw[col], lb = lnb[col];
    #pragma unroll
    for (int rr=0;rr<4;rr++){
      out[(size_t)(r0 + lg*4 + rr)*128 + col] = (xv[jt][rr]-mu[rr])*rstd[rr]*lw + lb;
    }
  }
}

// ---------------- host launch ----------------
extern "C" void kernel_launch(void* const* d_in, const int* in_sizes, int n_in,
                              void* d_out, int out_size, void* d_ws, size_t ws_size,
                              hipStream_t stream) {
  (void)in_sizes; (void)n_in; (void)out_size;
  const float* inp  = (const float*)d_in[0];
  const float* G    = (const float*)d_in[1];
  const float* xffw = (const float*)d_in[2];
  const float* xffb = (const float*)d_in[3];
  const float* w1   = (const float*)d_in[4];
  const float* b1   = (const float*)d_in[5];
  const float* w2   = (const float*)d_in[6];
  const float* b2   = (const float*)d_in[7];
  const float* lnw  = (const float*)d_in[8];
  const float* lnb  = (const float*)d_in[9];
  float* out = (float*)d_out;
  char* ws = (char*)d_ws;

  size_t off = 0;
  auto take = [&](size_t bytes)->char*{ char* p = ws + off; off += (bytes + 255) & ~(size_t)255; return p; };
  short* wqkv_b = (short*)take(384*128*2);
  short* gt_b   = (short*)take((size_t)1024*1024*2);
  short* w1_b   = (short*)take(128*128*2);
  short* w2_b   = (short*)take(128*128*2);
  short* qb     = (short*)take((size_t)48*1024*128*2);
  short* kTb    = (short*)take((size_t)48*128*1024*2);
  short* nvt    = (short*)take((size_t)48*128*1024*2);
  short* kgt    = (short*)take((size_t)48*1024*128*2);
  float* zbuf   = (float*)take((size_t)48*1024*4);
  short* pbuf   = (short*)take((size_t)4*1024*1024*2);
  float* csfin  = (float*)take((size_t)4*1024*4);
  int*   yidx   = (int*)take(256);
  float* mixres = (float*)take((size_t)48*6*78*4);
  short* vibuf  = (short*)take((size_t)48*1024*128*2);
  if (off > ws_size) return;

  prep_kernel<<<dim3(1056), dim3(256), 0, stream>>>(xffw, w1, w2, G, wqkv_b, w1_b, w2_b, gt_b);
  qkv_kernel<<<dim3(768), dim3(256), 0, stream>>>(inp, wqkv_b, xffb, qb, kTb, nvt);
  kg_kernel<<<dim3(768), dim3(256), 0, stream>>>(gt_b, kTb, kgt);
  fused_kernel<<<dim3(768), dim3(256), 0, stream>>>(qb, kgt, nvt, zbuf, pbuf, vibuf);
  colsum_kernel<<<dim3(64), dim3(256), 0, stream>>>(pbuf, zbuf, csfin);
  top2_kernel<<<dim3(4), dim3(256), 0, stream>>>(csfin, yidx);
  nvfixA_kernel<<<dim3(48), dim3(512), 0, stream>>>(nvt, yidx, mixres);
  ffn_kernel<<<dim3(768), dim3(256), 0, stream>>>(vibuf, inp, w1_b, w2_b, b1, b2, lnw, lnb,
                                                  qb, kgt, nvt, mixres, zbuf, yidx, out);
}

// Round 18
// 136.206 us; speedup vs baseline: 1.0400x; 1.0400x over previous
//
#include <hip/hip_runtime.h>
#include <hip/hip_bf16.h>

typedef __attribute__((ext_vector_type(8))) short bf16x8;
typedef __attribute__((ext_vector_type(4))) float f32x4;
typedef unsigned long long ull;

#define MFMA(a,b,c) __builtin_amdgcn_mfma_f32_16x16x32_bf16((a),(b),(c),0,0,0)
#define VMCNT(N) asm volatile("s_waitcnt vmcnt(%0)" :: "i"(N) : "memory")
#define EXP2(x) __builtin_amdgcn_exp2f(x)

__device__ __forceinline__ short f2bs(float f){
  union { float f; unsigned u; } x; x.f = f;
  unsigned r = (x.u + 0x7fffu + ((x.u >> 16) & 1u)) >> 16;
  return (short)r;
}
__device__ __forceinline__ float bs2f(short s){
  union { unsigned u; float f; } x; x.u = ((unsigned)(unsigned short)s) << 16;
  return x.f;
}

// async global->LDS, 16B per lane. LDS dest = wave-uniform base + lane*16.
__device__ __forceinline__ void gl2lds16(const void* g, void* l){
  __builtin_amdgcn_global_load_lds((const __attribute__((address_space(1))) void*)g,
                                   (__attribute__((address_space(3))) void*)l, 16, 0, 0);
}

__device__ __forceinline__ void merge2(ull& a1, ull& a2, ull b1, ull b2){
  ull n1 = min(a1, b1);
  ull n2 = min(max(a1, b1), min(a2, b2));
  a1 = n1; a2 = n2;
}

// ---------------- kernel 0: weight convert + G transpose ----------------
__global__ __launch_bounds__(256) void prep_kernel(const float* __restrict__ xffw,
                                                   const float* __restrict__ w1,
                                                   const float* __restrict__ w2,
                                                   const float* __restrict__ G,
                                                   short* __restrict__ wqkv_b,
                                                   short* __restrict__ w1_b,
                                                   short* __restrict__ w2_b,
                                                   short* __restrict__ gt){
  __shared__ float tile[32][33];
  int blk = blockIdx.x;
  if (blk >= 1024){
    int i = (blk-1024)*256 + threadIdx.x;
    int stride = 32*256;
    for (int idx = i; idx < 384*128; idx += stride) wqkv_b[idx] = f2bs(xffw[idx]);
    for (int idx = i; idx < 128*128; idx += stride) w1_b[idx] = f2bs(w1[idx]);
    for (int idx = i; idx < 128*128; idx += stride) w2_b[idx] = f2bs(w2[idx]);
    return;
  }
  int bx = blk & 31;
  int by = blk >> 5;
  int tx = threadIdx.x & 31, ty = threadIdx.x >> 5;
  #pragma unroll
  for (int j=0;j<4;j++){
    int n = by*32 + ty + j*8;
    tile[ty+j*8][tx] = G[(size_t)n*1024 + bx*32 + tx];
  }
  __syncthreads();
  #pragma unroll
  for (int j=0;j<4;j++){
    int m = bx*32 + ty + j*8;
    gt[(size_t)m*1024 + by*32 + tx] = f2bs(tile[tx][ty+j*8]);
  }
}

// ---------------- kernel 1: QKV projection ----------------
__global__ __launch_bounds__(256,3) void qkv_kernel(const float* __restrict__ inp,
                                                  const short* __restrict__ wqkv,
                                                  const float* __restrict__ bias,
                                                  short* __restrict__ q, short* __restrict__ kT,
                                                  short* __restrict__ nvt){
  __shared__ __align__(16) char smem[49152];
  int w = threadIdx.x >> 6, lane = threadIdx.x & 63;
  int lr = lane & 15, lg = lane >> 4;
  int r0 = blockIdx.x*64;
  int bt = blockIdx.x >> 4;
  int n0 = r0 & 1023;
  int rw = r0 + w*16;
  bf16x8 a[4];
  #pragma unroll
  for (int kc=0;kc<4;kc++){
    const float* ar = inp + (size_t)(rw+lr)*128 + kc*32 + lg*8;
    float4 f0 = *(const float4*)ar;
    float4 f1 = *(const float4*)(ar+4);
    bf16x8 t;
    t[0]=f2bs(f0.x); t[1]=f2bs(f0.y); t[2]=f2bs(f0.z); t[3]=f2bs(f0.w);
    t[4]=f2bs(f1.x); t[5]=f2bs(f1.y); t[6]=f2bs(f1.z); t[7]=f2bs(f1.w);
    a[kc]=t;
  }
  auto stageW = [&](int buf, int kc){
    #pragma unroll
    for (int t=0;t<6;t++){
      int r = (w*6+t)*16 + (lane>>2);
      int s = (lane&3) ^ ((r>>1)&3);
      gl2lds16(wqkv + (size_t)r*128 + kc*32 + s*8,
               smem + buf*24576 + (w*6+t)*1024);
    }
  };
  f32x4 acc[24];
  #pragma unroll
  for (int j=0;j<24;j++) acc[j] = f32x4{0.f,0.f,0.f,0.f};
  stageW(0, 0);
  int cur = 0;
  for (int kc=0; kc<4; kc++){
    if (kc < 3) { stageW(cur^1, kc+1); VMCNT(6); } else { VMCNT(0); }
    __builtin_amdgcn_s_barrier();
    __builtin_amdgcn_sched_barrier(0);
    const char* wb = smem + cur*24576;
    __builtin_amdgcn_s_setprio(1);
    #pragma unroll
    for (int jt=0;jt<24;jt++){
      int j = jt*16 + lr;
      bf16x8 b = *(const bf16x8*)(wb + (size_t)j*64 + ((lg ^ ((lr>>1)&3))*16));
      acc[jt] = MFMA(a[kc], b, acc[jt]);
    }
    __builtin_amdgcn_s_setprio(0);
    __builtin_amdgcn_s_barrier();
    cur ^= 1;
  }
  #pragma unroll
  for (int jt=0;jt<8;jt++){
    float bj = bias[jt*16+lr];
    #pragma unroll
    for (int rr=0;rr<4;rr++)
      q[(size_t)(rw + lg*4 + rr)*128 + jt*16 + lr] = f2bs(acc[jt][rr] + bj);
  }
  __syncthreads();
  short (*tb)[72] = (short(*)[72])smem;
  #pragma unroll
  for (int jt=8;jt<16;jt++){
    int d = (jt-8)*16 + lr;
    float bj = bias[jt*16+lr];
    #pragma unroll
    for (int rr=0;rr<4;rr++) tb[d][w*16 + lg*4 + rr] = f2bs(acc[jt][rr] + bj);
  }
  __syncthreads();
  #pragma unroll
  for (int it=0;it<4;it++){
    int idx = it*256 + threadIdx.x;
    int row = idx >> 3, c8 = (idx & 7)*8;
    *(bf16x8*)(kT + ((size_t)bt*128 + row)*1024 + n0 + c8) = *(const bf16x8*)&tb[row][c8];
  }
  __syncthreads();
  #pragma unroll
  for (int jt=16;jt<24;jt++){
    int c = (jt-16)*16 + lr;
    float bj = bias[jt*16+lr];
    #pragma unroll
    for (int rr=0;rr<4;rr++) tb[c][w*16 + lg*4 + rr] = f2bs(acc[jt][rr] + bj);
  }
  __syncthreads();
  #pragma unroll
  for (int it=0;it<4;it++){
    int idx = it*256 + threadIdx.x;
    int row = idx >> 3, c8 = (idx & 7)*8;
    *(bf16x8*)(nvt + ((size_t)bt*128 + row)*1024 + n0 + c8) = *(const bf16x8*)&tb[row][c8];
  }
}

// ---------------- kernel 2: KGT = (K^T G)*log2e/sqrt(128) ----------------
__global__ __launch_bounds__(256,3) void kg_kernel(const short* __restrict__ gt,
                                                   const short* __restrict__ kT,
                                                   short* __restrict__ kgt){
  __shared__ __align__(16) short gtl[2][64*64];
  __shared__ __align__(16) short ktl[2][128*64];
  int lb = (blockIdx.x & 7)*96 + (blockIdx.x >> 3);   // XCD swizzle
  int bt = lb >> 4;
  int mt = lb & 15;
  int w = threadIdx.x>>6, lane = threadIdx.x&63, lr = lane&15, lg = lane>>4;
  int mblk = mt*64;
  const short* kbase = kT + (size_t)bt*128*1024;
  auto stage = [&](int b, int nc){
    int n0 = nc*64;
    #pragma unroll
    for (int t=0;t<2;t++){
      int row = w*16 + t*8 + (lane>>3);
      int cswz = ((lane&7)*16) ^ ((row&7)<<4);
      gl2lds16(gt + (size_t)(mblk+row)*1024 + n0 + (cswz>>1),
               (char*)gtl[b] + w*2048 + t*1024);
    }
    #pragma unroll
    for (int t=0;t<4;t++){
      int row = w*32 + t*8 + (lane>>3);
      int cswz = ((lane&7)*16) ^ ((row&7)<<4);
      gl2lds16(kbase + (size_t)row*1024 + n0 + (cswz>>1),
               (char*)ktl[b] + w*4096 + t*1024);
    }
  };
  f32x4 acc[8];
  #pragma unroll
  for (int i=0;i<8;i++) acc[i] = f32x4{0.f,0.f,0.f,0.f};
  stage(0, 0);
  int cur = 0;
  for (int nc=0; nc<16; nc++){
    if (nc < 15) { stage(cur^1, nc+1); VMCNT(6); } else { VMCNT(0); }
    __builtin_amdgcn_s_barrier();
    __builtin_amdgcn_sched_barrier(0);
    __builtin_amdgcn_s_setprio(1);
    #pragma unroll
    for (int ks=0;ks<2;ks++){
      int arl = w*16 + lr;
      int acb = ks*64 + lg*16;
      bf16x8 af = *(const bf16x8*)((const char*)gtl[cur] + arl*128 + (acb ^ ((arl&7)<<4)));
      #pragma unroll
      for (int dt=0;dt<8;dt++){
        int brl = dt*16 + lr;
        bf16x8 bf = *(const bf16x8*)((const char*)ktl[cur] + brl*128 + (acb ^ ((brl&7)<<4)));
        acc[dt] = MFMA(af, bf, acc[dt]);
      }
    }
    __builtin_amdgcn_s_setprio(0);
    __builtin_amdgcn_s_barrier();
    cur ^= 1;
  }
  // 1/sqrt(128) * log2(e): exps downstream become single v_exp (exp2)
  const float SCALE = 0.08838834764831845f * 1.4426950408889634f;
  int m = mblk + w*16 + lg*4;
  #pragma unroll
  for (int dt=0;dt<8;dt++){
    #pragma unroll
    for (int rr=0;rr<4;rr++){
      kgt[((size_t)(bt*1024 + m + rr))*128 + dt*16 + lr] = f2bs(acc[dt][rr]*SCALE);
    }
  }
}

// ---------------- kernel 3: FUSED attn, phase-alternating; R12 XOR p-layout ----------------
// LDS = 16KB kgl + 16KB nvl + 8KB p = 40960B.
__global__ __launch_bounds__(256,3) void fused_kernel(const short* __restrict__ q,
                                                      const short* __restrict__ kgt,
                                                      const short* __restrict__ nvt,
                                                      float* __restrict__ zbuf,
                                                      short* __restrict__ pbuf,
                                                      short* __restrict__ vib){
  __shared__ __align__(16) short kgl[64*128];
  __shared__ __align__(16) short nvl[128*64];
  __shared__ __align__(16) char  p_raw[8192];   // [wave][16][64] bf16, byte ^= (row&7)<<4
  int lb = (blockIdx.x & 7)*96 + (blockIdx.x >> 3);   // XCD swizzle
  int bt = lb >> 4;
  int rblk = lb & 15;
  int w = threadIdx.x>>6, lane = threadIdx.x&63, lr = lane&15, lg = lane>>4;
  int r0 = rblk*64 + w*16;
  bool is5 = (bt % 12) == 5;
  int bq = bt / 12;
  const short* qrow = q + ((size_t)(bt*1024 + r0 + lr))*128;
  bf16x8 a[4];
  #pragma unroll
  for (int kc=0;kc<4;kc++) a[kc] = *(const bf16x8*)(qrow + kc*32 + lg*8);
  const short* kgb = kgt + (size_t)bt*1024*128;
  const short* nvb = nvt + (size_t)bt*128*1024;
  char* pw = p_raw + w*2048;
  auto stage_kg = [&](int mc){
    int m0 = mc*64;
    #pragma unroll
    for (int t=0;t<4;t++){
      int row = w*16 + t*4 + (lane>>4);
      int cswz = ((lane&15)*16) ^ ((row&7)<<4);
      gl2lds16(kgb + (size_t)(m0+row)*128 + (cswz>>1),
               (char*)kgl + w*4096 + t*1024);
    }
  };
  auto stage_nv = [&](int mc){
    int m0 = mc*64;
    #pragma unroll
    for (int t=0;t<4;t++){
      int row = w*32 + t*8 + (lane>>3);
      int cswz = ((lane&7)*16) ^ ((row&7)<<4);
      gl2lds16(nvb + (size_t)row*1024 + m0 + (cswz>>1),
               (char*)nvl + w*4096 + t*1024);
    }
  };
  f32x4 acc[8];
  #pragma unroll
  for (int i=0;i<8;i++) acc[i] = f32x4{0.f,0.f,0.f,0.f};
  float zacc[4] = {0.f,0.f,0.f,0.f};
  // prologue
  stage_kg(0);
  stage_nv(0);
  VMCNT(0);
  __builtin_amdgcn_s_barrier();
  __builtin_amdgcn_sched_barrier(0);
  for (int mc=0; mc<16; mc++){
    int m0 = mc*64;
    // ---- e-phase: reads kgl only ----
    __builtin_amdgcn_s_setprio(1);
    #pragma unroll
    for (int s=0;s<4;s++){
      f32x4 e = f32x4{0.f,0.f,0.f,0.f};
      #pragma unroll
      for (int kc=0;kc<4;kc++){
        int rl = s*16 + lr;
        int cb = kc*64 + lg*16;
        bf16x8 kb = *(const bf16x8*)((const char*)kgl + rl*256 + (cb ^ ((rl&7)<<4)));
        e = MFMA(a[kc], kb, e);
      }
      #pragma unroll
      for (int rr=0;rr<4;rr++){
        int row = lg*4+rr;
        float p = EXP2(fminf(e[rr], 80.f));   // kgt carries log2e; raw v_exp_f32
        zacc[rr] += p;
        *(short*)(pw + ((row*128 + (s*16+lr)*2) ^ ((row&7)<<4))) = f2bs(p);
      }
    }
    __builtin_amdgcn_s_setprio(0);
    __builtin_amdgcn_s_barrier();           // kgl reads done everywhere
    if (mc < 15) stage_kg(mc+1);            // overwrite kgl; overlaps PV
    if (mc < 15) { VMCNT(4); } else { VMCNT(0); }  // nv(mc) landed
    __builtin_amdgcn_s_barrier();
    __builtin_amdgcn_sched_barrier(0);
    // ---- PV phase: reads p (own wave, single b128) + nvl ----
    bf16x8 pa0 = *(const bf16x8*)(pw + ((lr*128 + lg*16) ^ ((lr&7)<<4)));
    bf16x8 pa1 = *(const bf16x8*)(pw + ((lr*128 + 64 + lg*16) ^ ((lr&7)<<4)));
    __builtin_amdgcn_s_setprio(1);
    #pragma unroll
    for (int ct=0; ct<8; ct++){
      int c = ct*16 + lr;
      int mb0 = lg*16;
      int mb1 = 64 + lg*16;
      bf16x8 nb0 = *(const bf16x8*)((const char*)nvl + c*128 + (mb0 ^ ((c&7)<<4)));
      bf16x8 nb1 = *(const bf16x8*)((const char*)nvl + c*128 + (mb1 ^ ((c&7)<<4)));
      acc[ct] = MFMA(pa0, nb0, acc[ct]);
      acc[ct] = MFMA(pa1, nb1, acc[ct]);
    }
    __builtin_amdgcn_s_setprio(0);
    if (is5){
      // dump unnormalized P tile (bf16) for deterministic col-sums
      #pragma unroll
      for (int tt=0; tt<4; tt++){
        int row = tt*4 + (lane>>4);     // 0..15
        int m = (lane&15)*4;            // 0..60
        ull v = *(const ull*)(pw + ((row*128 + m*2) ^ ((row&7)<<4)));
        *(ull*)(pbuf + ((size_t)bq*1024 + r0 + row)*1024 + m0 + m) = v;
      }
    }
    __builtin_amdgcn_s_barrier();           // nvl reads done everywhere
    if (mc < 15) { stage_nv(mc+1); VMCNT(4); } else { VMCNT(0); }  // kg(mc+1) landed
    __builtin_amdgcn_s_barrier();
    __builtin_amdgcn_sched_barrier(0);
  }
  // z: reduce across the 16 lr lanes (cols)
  #pragma unroll
  for (int d=1;d<16;d<<=1){
    #pragma unroll
    for (int rr=0;rr<4;rr++) zacc[rr] += __shfl_xor(zacc[rr], d, 64);
  }
  if (lr==0){
    #pragma unroll
    for (int rr=0;rr<4;rr++) zbuf[(size_t)bt*1024 + r0 + lg*4 + rr] = zacc[rr];
  }
  float inv[4];
  #pragma unroll
  for (int rr=0;rr<4;rr++) inv[rr] = 1.0f/zacc[rr];
  #pragma unroll
  for (int ct=0;ct<8;ct++){
    #pragma unroll
    for (int rr=0;rr<4;rr++){
      vib[((size_t)(bt*1024 + r0 + lg*4 + rr))*128 + ct*16 + lr] = f2bs(acc[ct][rr]*inv[rr]);
    }
  }
}

// ---------------- kernel 3b: deterministic col sums from dumped P ----------------
__global__ __launch_bounds__(256) void colsum_kernel(const short* __restrict__ pbuf,
                                                     const float* __restrict__ zbuf,
                                                     float* __restrict__ csfinal){
  __shared__ float part[4][64];
  int b = blockIdx.x >> 4, mg = blockIdx.x & 15;
  int t = threadIdx.x;
  int mcol = mg*64 + (t & 63);
  int rq = t >> 6;
  const short* pb = pbuf + (size_t)b*1024*1024;
  const float* zb = zbuf + (size_t)(b*12 + 5)*1024;
  float s = 0.f;
  for (int r = rq*256; r < rq*256 + 256; r++){
    s += bs2f(pb[(size_t)r*1024 + mcol]) * (1.0f/zb[r]);
  }
  part[rq][t & 63] = s;
  __syncthreads();
  if (t < 64){
    float cs = (part[0][t] + part[1][t]) + (part[2][t] + part[3][t]);
    csfinal[(size_t)b*1024 + mg*64 + t] = cs;
  }
}

// ---------------- kernel 4: parallel deterministic top-2-min -> y per batch ----------------
__global__ __launch_bounds__(256) void top2_kernel(const float* __restrict__ csfinal,
                                                   int* __restrict__ yidx){
  __shared__ ull s1[4], s2[4];
  int b = blockIdx.x;
  ull b1 = ~0ull, b2 = ~0ull;
  #pragma unroll
  for (int j=0;j<4;j++){
    int col = j*256 + threadIdx.x;
    float s = csfinal[(size_t)b*1024 + col];
    union { float f; unsigned u; } cv; cv.f = s;
    ull key = ((ull)cv.u << 32) | (unsigned)col;
    merge2(b1, b2, key, ~0ull);
  }
  #pragma unroll
  for (int d=1;d<64;d<<=1){
    ull o1 = __shfl_xor(b1, d, 64);
    ull o2 = __shfl_xor(b2, d, 64);
    merge2(b1, b2, o1, o2);
  }
  int w = threadIdx.x >> 6;
  if ((threadIdx.x & 63) == 0){ s1[w] = b1; s2[w] = b2; }
  __syncthreads();
  if (threadIdx.x == 0){
    ull r1 = s1[0], r2 = s2[0];
    merge2(r1, r2, s1[1], s2[1]);
    merge2(r1, r2, s1[2], s2[2]);
    merge2(r1, r2, s1[3], s2[3]);
    yidx[b] = (int)(r2 & 0xffffffffu);
  }
}

// ---------------- kernel 5: mixup averages from pristine NV ----------------
__global__ void nvfixA_kernel(const short* __restrict__ nvt, const int* __restrict__ yidx,
                              float* __restrict__ mixres){
  int bt = blockIdx.x; int b = bt/12, t = bt%12;
  int y = yidx[b];
  int y_start = max(y-6, 0), y_end = min(y+12, 1024);
  int bs, j0, cnt;
  if (y_end > 1024-6){ bs = 1; j0 = y_start; cnt = y_end - y_start; }
  else { bs = 6; j0 = y_start/6; cnt = y_end/6 - j0; }
  int items = bs*78;
  int idx = threadIdx.x;
  if (idx >= items) return;
  int i = idx / 78, c = idx % 78;
  const short* nvb = nvt + (size_t)bt*128*1024;
  float acc = 0.f;
  for (int jj=0;jj<cnt;jj++){
    int col = (j0+jj)*bs + i;
    float gv;
    if (t == 5 && col == y){
      float wsum = 0.f, mv = 0.f;
      #pragma unroll
      for (int tp=0;tp<5;tp++){
        float d = (float)tp - 4.0f;
        float w = __expf(-d*d/200.0f);
        wsum += w;
        mv += w * bs2f(nvt[((size_t)(b*12+tp)*128 + c)*1024 + y]);
      }
      gv = mv / wsum;
    } else {
      gv = bs2f(nvb[(size_t)c*1024 + col]);
    }
    acc += gv;
  }
  mixres[((size_t)bt*6 + i)*78 + c] = acc / (float)cnt;
}

// ---------------- kernel 7: FFN + fused rank<=6 correction + residual + LayerNorm ----------------
// LDS: wl 32768 + hb 16896 = 49664 -> 3 blocks/CU. Prologue buffers union'd into hb.
__global__ __launch_bounds__(256,3) void ffn_kernel(const short* __restrict__ vib,
                                                  const float* __restrict__ inp,
                                                  const short* __restrict__ w1b,
                                                  const short* __restrict__ w2b,
                                                  const float* __restrict__ b1,
                                                  const float* __restrict__ b2,
                                                  const float* __restrict__ lnw,
                                                  const float* __restrict__ lnb,
                                                  const short* __restrict__ qb,
                                                  const short* __restrict__ kgt,
                                                  const short* __restrict__ nvt,
                                                  const float* __restrict__ mixres,
                                                  const float* __restrict__ zbuf,
                                                  const int* __restrict__ yidx,
                                                  float* __restrict__ out){
  __shared__ __align__(16) short wl[128*128];       // 32768
  __shared__ __align__(16) char  hb[4*16*132*2];    // 16896; union: prologue then h
  short* kcolT = (short*)hb;                        // [16][136-pitch shorts] 4352 B
  float* delta = (float*)(hb + 4352);               // [6][80] f32, 1920 B
  float* p_sh  = (float*)(hb + 4352 + 1920);        // [64][6] f32, 1536 B
  short* hs    = (short*)hb;                        // [(w*16+row)*132 + col] after barrier
  int w = threadIdx.x>>6, lane = threadIdx.x&63, lr = lane&15, lg = lane>>4;
  int bt = blockIdx.x >> 4;
  int nb = (blockIdx.x & 15)*64;      // local row base within bt
  int r0 = blockIdx.x*64 + w*16;      // global row base of this wave
  int b = bt/12;
  int y = yidx[b];
  int y_end = min(y+12, 1024);
  int bs = (y_end > 1024-6) ? 1 : 6;
  // phase A: kcolT rows (coalesced copy of kgt rows y..y+5, zero-fill i>=bs) + delta (f32)
  for (int idx = threadIdx.x; idx < 16*128; idx += 256){
    int i = idx >> 7, d = idx & 127;
    kcolT[i*136 + d] = (i < bs) ? kgt[((size_t)(bt*1024 + y + i))*128 + d] : (short)0;
  }
  for (int idx = threadIdx.x; idx < 6*78; idx += 256){
    int i = idx / 78, c = idx % 78;
    float dv = 0.f;
    if (i < bs){
      float avg = mixres[((size_t)bt*6 + i)*78 + c];
      int ti = (int)avg;                   // trunc toward zero
      unsigned char u = (unsigned char)ti; // wrap mod 256
      dv = (float)u - bs2f(nvt[((size_t)bt*128 + c)*1024 + (y+i)]);
    }
    delta[i*80 + c] = dv;
  }
  __syncthreads();
  // phase B: p via MFMA (same operand layout as fused => bit-identical e)
  {
    const short* qr = qb + ((size_t)(bt*1024 + nb + w*16 + lr))*128;
    bf16x8 qa[4];
    #pragma unroll
    for (int kc=0;kc<4;kc++) qa[kc] = *(const bf16x8*)(qr + kc*32 + lg*8);
    f32x4 ep = f32x4{0.f,0.f,0.f,0.f};
    #pragma unroll
    for (int kc=0;kc<4;kc++){
      bf16x8 kb = *(const bf16x8*)((const char*)kcolT + lr*272 + kc*64 + lg*16);
      ep = MFMA(qa[kc], kb, ep);
    }
    #pragma unroll
    for (int rr=0;rr<4;rr++){
      int row = w*16 + lg*4 + rr;          // block-local 0..63
      float pv = 0.f;
      if (lr < bs){
        float z = zbuf[(size_t)bt*1024 + nb + row];
        pv = EXP2(fminf(ep[rr], 80.f)) / z;
      }
      if (lr < 6) p_sh[row*6 + lr] = pv;
    }
  }
  auto stageW = [&](const short* src){
    #pragma unroll
    for (int t=0;t<8;t++){
      int r = (w*8+t)*4 + (lane>>4);
      int s = (lane&15) ^ (r&7);
      gl2lds16(src + (size_t)r*128 + s*8, (char*)wl + (w*8+t)*1024);
    }
  };
  stageW(w1b);
  __syncthreads();   // drains DMA + p_sh/delta writes
  // corrected A-frags
  float pr6[6];
  #pragma unroll
  for (int i=0;i<6;i++) pr6[i] = p_sh[(w*16 + lr)*6 + i];
  bf16x8 a[4];
  #pragma unroll
  for (int kc=0;kc<4;kc++){
    bf16x8 v = *(const bf16x8*)(vib + (size_t)(r0+lr)*128 + kc*32 + lg*8);
    #pragma unroll
    for (int e=0;e<8;e++){
      int col = kc*32 + lg*8 + e;
      if (col < 78){
        float ds = 0.f;
        #pragma unroll
        for (int i=0;i<6;i++) ds += pr6[i] * delta[i*80 + col];
        v[e] = f2bs(bs2f(v[e]) + ds);
      }
    }
    a[kc] = v;
  }
  __syncthreads();   // all prologue reads done before h overwrites hb
  f32x4 acc[8];
  #pragma unroll
  for (int i=0;i<8;i++) acc[i] = f32x4{0.f,0.f,0.f,0.f};
  __builtin_amdgcn_s_setprio(1);
  #pragma unroll
  for (int kc=0;kc<4;kc++){
    #pragma unroll
    for (int jt=0;jt<8;jt++){
      bf16x8 bfr = *(const bf16x8*)((const char*)wl + (size_t)(jt*16+lr)*256 + (((kc*4+lg) ^ (lr&7))*16));
      acc[jt] = MFMA(a[kc], bfr, acc[jt]);
    }
  }
  __builtin_amdgcn_s_setprio(0);
  #pragma unroll
  for (int jt=0;jt<8;jt++){
    float bj = b1[jt*16+lr];
    #pragma unroll
    for (int rr=0;rr<4;rr++){
      float x = acc[jt][rr] + bj;
      float g = 0.5f*x*(1.0f + erff(x*0.70710678118654752f));
      hs[(w*16 + lg*4 + rr)*132 + jt*16 + lr] = f2bs(g);
    }
  }
  __syncthreads();
  stageW(w2b);
  bf16x8 ha[4];
  #pragma unroll
  for (int kc=0;kc<4;kc++){
    const short* hp = &hs[(w*16 + lr)*132 + kc*32 + lg*8];
    ull lo = *(const ull*)hp;
    ull hi = *(const ull*)(hp + 4);
    ((ull*)&ha[kc])[0] = lo; ((ull*)&ha[kc])[1] = hi;
  }
  __syncthreads();
  f32x4 acc2[8];
  #pragma unroll
  for (int i=0;i<8;i++) acc2[i] = f32x4{0.f,0.f,0.f,0.f};
  __builtin_amdgcn_s_setprio(1);
  #pragma unroll
  for (int kc=0;kc<4;kc++){
    #pragma unroll
    for (int jt=0;jt<8;jt++){
      bf16x8 bfr = *(const bf16x8*)((const char*)wl + (size_t)(jt*16+lr)*256 + (((kc*4+lg) ^ (lr&7))*16));
      acc2[jt] = MFMA(ha[kc], bfr, acc2[jt]);
    }
  }
  __builtin_amdgcn_s_setprio(0);
  float xv[8][4];
  #pragma unroll
  for (int jt=0;jt<8;jt++){
    float bj = b2[jt*16+lr];
    #pragma unroll
    for (int rr=0;rr<4;rr++){
      xv[jt][rr] = acc2[jt][rr] + bj + inp[(size_t)(r0 + lg*4 + rr)*128 + jt*16 + lr];
    }
  }
  float mu[4], rstd[4];
  #pragma unroll
  for (int rr=0;rr<4;rr++){
    float s = 0.f;
    #pragma unroll
    for (int jt=0;jt<8;jt++) s += xv[jt][rr];
    #pragma unroll
    for (int m=1;m<16;m<<=1) s += __shfl_xor(s, m, 64);
    mu[rr] = s * (1.0f/128.0f);
  }
  #pragma unroll
  for (int rr=0;rr<4;rr++){
    float s = 0.f;
    #pragma unroll
    for (int jt=0;jt<8;jt++){ float d = xv[jt][rr]-mu[rr]; s += d*d; }
    #pragma unroll
    for (int m=1;m<16;m<<=1) s += __shfl_xor(s, m, 64);
    rstd[rr] = rsqrtf(s * (1.0f/128.0f) + 1e-5f);
  }
  #pragma unroll
  for (int jt=0;jt<8;jt++){
    int col = jt*16 + lr;
    float lw = lnw[col], lb = lnb[col];
    #pragma unroll
    for (int rr=0;rr<4;rr++){
      out[(size_t)(r0 + lg*4 + rr)*128 + col] = (xv[jt][rr]-mu[rr])*rstd[rr]*lw + lb;
    }
  }
}

// ---------------- host launch ----------------
extern "C" void kernel_launch(void* const* d_in, const int* in_sizes, int n_in,
                              void* d_out, int out_size, void* d_ws, size_t ws_size,
                              hipStream_t stream) {
  (void)in_sizes; (void)n_in; (void)out_size;
  const float* inp  = (const float*)d_in[0];
  const float* G    = (const float*)d_in[1];
  const float* xffw = (const float*)d_in[2];
  const float* xffb = (const float*)d_in[3];
  const float* w1   = (const float*)d_in[4];
  const float* b1   = (const float*)d_in[5];
  const float* w2   = (const float*)d_in[6];
  const float* b2   = (const float*)d_in[7];
  const float* lnw  = (const float*)d_in[8];
  const float* lnb  = (const float*)d_in[9];
  float* out = (float*)d_out;
  char* ws = (char*)d_ws;

  size_t off = 0;
  auto take = [&](size_t bytes)->char*{ char* p = ws + off; off += (bytes + 255) & ~(size_t)255; return p; };
  short* wqkv_b = (short*)take(384*128*2);
  short* gt_b   = (short*)take((size_t)1024*1024*2);
  short* w1_b   = (short*)take(128*128*2);
  short* w2_b   = (short*)take(128*128*2);
  short* qb     = (short*)take((size_t)48*1024*128*2);
  short* kTb    = (short*)take((size_t)48*128*1024*2);
  short* nvt    = (short*)take((size_t)48*128*1024*2);
  short* kgt    = (short*)take((size_t)48*1024*128*2);
  float* zbuf   = (float*)take((size_t)48*1024*4);
  short* pbuf   = (short*)take((size_t)4*1024*1024*2);
  float* csfin  = (float*)take((size_t)4*1024*4);
  int*   yidx   = (int*)take(256);
  float* mixres = (float*)take((size_t)48*6*78*4);
  short* vibuf  = (short*)take((size_t)48*1024*128*2);
  if (off > ws_size) return;

  prep_kernel<<<dim3(1056), dim3(256), 0, stream>>>(xffw, w1, w2, G, wqkv_b, w1_b, w2_b, gt_b);
  qkv_kernel<<<dim3(768), dim3(256), 0, stream>>>(inp, wqkv_b, xffb, qb, kTb, nvt);
  kg_kernel<<<dim3(768), dim3(256), 0, stream>>>(gt_b, kTb, kgt);
  fused_kernel<<<dim3(768), dim3(256), 0, stream>>>(qb, kgt, nvt, zbuf, pbuf, vibuf);
  colsum_kernel<<<dim3(64), dim3(256), 0, stream>>>(pbuf, zbuf, csfin);
  top2_kernel<<<dim3(4), dim3(256), 0, stream>>>(csfin, yidx);
  nvfixA_kernel<<<dim3(48), dim3(512), 0, stream>>>(nvt, yidx, mixres);
  ffn_kernel<<<dim3(768), dim3(256), 0, stream>>>(vibuf, inp, w1_b, w2_b, b1, b2, lnw, lnb,
                                                  qb, kgt, nvt, mixres, zbuf, yidx, out);
}